// Round 23
// baseline (30.311 us; speedup 1.0000x reference)
//
#include <hip/hip_runtime.h>

#define GRIDN 64
#define NVOX (GRIDN * GRIDN * GRIDN)
#define VOXF (1.0f / 64.0f)
#define QCUT 12.0f               // contribution cut at e^-6 per (gaussian,voxel)
#define EXPSCL (-0.72134752044f) // -0.5 * log2(e)
#define CAP 2048                 // per-tile survivor-list capacity (worst ~600)

// Workspace layout (float-element offsets), N=4096:
//  rec[N]      16 floats each (3x float4 used)          [0, 65536)
//  tilelist[512][CAP] int                               [65536, 65536+512*CAP)
//  cnt[512] int                                          after
#define WS_REC 0
#define WS_TL  (16 * 4096)
#define WS_CNT (WS_TL + 512 * CAP)

// Kernel 1: blocks 0..3 build per-gaussian records + radii; blocks 4..515
// each own one 8x8x8 tile and cull ALL gaussians with inline-recomputed
// params (no dependency on the record blocks -> race-free fusion), writing
// a stable-compacted index list to global. 1024 threads (16 waves).
__global__ __launch_bounds__(1024) void prep_kernel(
    const float* __restrict__ means, const float* __restrict__ dens,
    const float* __restrict__ scales, const float* __restrict__ rots,
    float* __restrict__ rec, int* __restrict__ tilelist, int* __restrict__ cntg,
    float* __restrict__ radii_out, int N)
{
    __shared__ unsigned long long cmask[64];
    const int b = blockIdx.x;
    const int tid = threadIdx.x;

    if (b < 4) {
        const int i = (b << 10) + tid;
        if (i >= N) return;

        float qw = rots[i * 4 + 0], qx = rots[i * 4 + 1];
        float qy = rots[i * 4 + 2], qz = rots[i * 4 + 3];
        float inm = rsqrtf(qw * qw + qx * qx + qy * qy + qz * qz);
        qw *= inm; qx *= inm; qy *= inm; qz *= inm;
        float r00 = 1.f - 2.f * (qy * qy + qz * qz);
        float r01 = 2.f * (qx * qy - qw * qz);
        float r02 = 2.f * (qx * qz + qw * qy);
        float r10 = 2.f * (qx * qy + qw * qz);
        float r11 = 1.f - 2.f * (qx * qx + qz * qz);
        float r12 = 2.f * (qy * qz - qw * qx);
        float r20 = 2.f * (qx * qz - qw * qy);
        float r21 = 2.f * (qy * qz + qw * qx);
        float r22 = 1.f - 2.f * (qx * qx + qy * qy);

        float s0 = scales[i * 3 + 0], s1 = scales[i * 3 + 1], s2 = scales[i * 3 + 2];
        float v0 = s0 * s0, v1 = s1 * s1, v2 = s2 * s2;
        float i0 = 1.f / v0, i1 = 1.f / v1, i2 = 1.f / v2;

        // Sinv = R diag(1/s^2) R^T, scaled by EXPSCL (negative)
        float A = (r00 * r00 * i0 + r01 * r01 * i1 + r02 * r02 * i2) * EXPSCL;
        float B = (r10 * r10 * i0 + r11 * r11 * i1 + r12 * r12 * i2) * EXPSCL;
        float C = (r20 * r20 * i0 + r21 * r21 * i1 + r22 * r22 * i2) * EXPSCL;
        float D = (r00 * r10 * i0 + r01 * r11 * i1 + r02 * r12 * i2) * EXPSCL;
        float E = (r00 * r20 * i0 + r01 * r21 * i1 + r02 * r22 * i2) * EXPSCL;
        float F = (r10 * r20 * i0 + r11 * r21 * i1 + r12 * r22 * i2) * EXPSCL;

        float de = fmaxf(dens[i], 1e-30f);
        float4* R = (float4*)(rec + (size_t)i * 16);
        float4 w0; w0.x = A; w0.y = B; w0.z = C; w0.w = 2.f * D;
        float4 w1; w1.x = 2.f * E; w1.y = 2.f * F; w1.z = -0.25f / A; w1.w = log2f(de);
        float4 w2; w2.x = means[i * 3 + 0]; w2.y = means[i * 3 + 1];
        w2.z = means[i * 3 + 2]; w2.w = 0.f;
        R[0] = w0; R[1] = w1; R[2] = w2;

        radii_out[i] = ceilf(fmaxf(s0, fmaxf(s1, s2)) * 3.0f * 64.0f);
        return;
    }

    // ---- tile block: cull all gaussians against tile tb ----
    const int tb = b - 4;
    const int lane = tid & 63, wave = tid >> 6;
    const int tX = tb & 7, tY = (tb >> 3) & 7, tZ = tb >> 6;   // 8x8x8 tiles
    const float lox = ((tX << 3) + 0.5f) * VOXF, hix = ((tX << 3) + 7.5f) * VOXF;
    const float loy = ((tY << 3) + 0.5f) * VOXF, hiy = ((tY << 3) + 7.5f) * VOXF;
    const float loz = ((tZ << 3) + 0.5f) * VOXF, hiz = ((tZ << 3) + 7.5f) * VOXF;

    const int nch = (N + 63) >> 6;
    #pragma unroll
    for (int k = 0; k < 4; ++k) {
        const int c = (k << 4) | wave;
        unsigned long long bal = 0ull;
        if (c < nch) {
            const int gi = (c << 6) + lane;
            const int gc = gi < N ? gi : N - 1;
            // inline cull-param recompute from raw inputs
            float qw = rots[gc * 4 + 0], qx = rots[gc * 4 + 1];
            float qy = rots[gc * 4 + 2], qz = rots[gc * 4 + 3];
            float inm = rsqrtf(qw * qw + qx * qx + qy * qy + qz * qz);
            float w = qw * inm, a = qx * inm, bq = qy * inm, cq = qz * inm;
            float r00 = 1.f - 2.f * (bq * bq + cq * cq);
            float r01 = 2.f * (a * bq - w * cq);
            float r02 = 2.f * (a * cq + w * bq);
            float r10 = 2.f * (a * bq + w * cq);
            float r11 = 1.f - 2.f * (a * a + cq * cq);
            float r12 = 2.f * (bq * cq - w * a);
            float r20 = 2.f * (a * cq - w * bq);
            float r21 = 2.f * (bq * cq + w * a);
            float r22 = 1.f - 2.f * (a * a + bq * bq);
            float s0 = scales[gc * 3 + 0], s1 = scales[gc * 3 + 1], s2 = scales[gc * 3 + 2];
            float v0 = s0 * s0, v1 = s1 * s1, v2 = s2 * s2;
            float Cxx = r00 * r00 * v0 + r01 * r01 * v1 + r02 * r02 * v2;
            float Cyy = r10 * r10 * v0 + r11 * r11 * v1 + r12 * r12 * v2;
            float Czz = r20 * r20 * v0 + r21 * r21 * v1 + r22 * r22 * v2;
            float de = fmaxf(dens[gc], 1e-30f);
            float qeff = fmaxf(QCUT + 2.0f * logf(de), 0.0f);
            float rx = sqrtf(qeff * Cxx), ry = sqrtf(qeff * Cyy), rz = sqrtf(qeff * Czz);
            float sph = qeff * fmaxf(v0, fmaxf(v1, v2));
            float mx = means[gc * 3 + 0], my = means[gc * 3 + 1], mz = means[gc * 3 + 2];

            float cx = fminf(fmaxf(mx, lox), hix) - mx;
            float cy = fminf(fmaxf(my, loy), hiy) - my;
            float cz = fminf(fmaxf(mz, loz), hiz) - mz;
            float d2 = fmaf(cx, cx, fmaf(cy, cy, cz * cz));
            bool keep = (gi < N) && (d2 <= sph)
                && (mx + rx >= lox) && (mx - rx <= hix)
                && (my + ry >= loy) && (my - ry <= hiy)
                && (mz + rz >= loz) && (mz - rz <= hiz);
            bal = __ballot(keep);
        }
        if (lane == 0) cmask[c] = bal;
    }
    __syncthreads();

    // scan over 64 chunk-masks (all waves compute identically)
    unsigned long long mk = cmask[lane];
    int pc = __popcll(mk);
    int incl = pc;
    #pragma unroll
    for (int d = 1; d < 64; d <<= 1) {
        int t2 = __shfl_up(incl, d, 64);
        if (lane >= d) incl += t2;
    }
    const int excl = incl - pc;
    int cnt = __builtin_amdgcn_readlane(incl, 63);
    if (cnt > CAP) cnt = CAP;    // stable truncation (deterministic)

    // stable scatter of survivor indices to the global per-tile list
    int* tl = tilelist + (size_t)tb * CAP;
    #pragma unroll
    for (int k = 0; k < 4; ++k) {
        const int c = (k << 4) | wave;
        unsigned long long mc = cmask[c];
        if (mc == 0ull) continue;
        int bse = __builtin_amdgcn_readlane(excl, c);
        if ((mc >> lane) & 1ull) {
            int pre = __popcll(mc & ((1ull << lane) - 1ull));
            int pos = bse + pre;
            if (pos < CAP) tl[pos] = (c << 6) + lane;
        }
    }
    if (tid == 0) cntg[tb] = cnt;
}

// 8-voxel-strip body; exp2(very negative)=0 exactly -> no strip test.
#define BODY8(v0_, v1_, v2_) do {                                             \
    float dy = py - v2_.y, dz = pz - v2_.z;                                   \
    float tt  = fmaf(v1_.y, dy, v0_.z * dz);                                  \
    float qyz = fmaf(v0_.y * dy, dy, fmaf(tt, dz, v1_.w));                    \
    float gx  = fmaf(v0_.w, dy, v1_.x * dz);                                  \
    float dx0 = px - v2_.x;                                                   \
    float dx1 = dx0 + VOXF,        dx2 = dx0 + 2.f * VOXF;                    \
    float dx3 = dx0 + 3.f * VOXF,  dx4 = dx0 + 4.f * VOXF;                    \
    float dx5 = dx0 + 5.f * VOXF,  dx6 = dx0 + 6.f * VOXF;                    \
    float dx7 = dx0 + 7.f * VOXF;                                             \
    accL.x += __builtin_amdgcn_exp2f(fmaf(dx0, fmaf(v0_.x, dx0, gx), qyz));   \
    accL.y += __builtin_amdgcn_exp2f(fmaf(dx1, fmaf(v0_.x, dx1, gx), qyz));   \
    accL.z += __builtin_amdgcn_exp2f(fmaf(dx2, fmaf(v0_.x, dx2, gx), qyz));   \
    accL.w += __builtin_amdgcn_exp2f(fmaf(dx3, fmaf(v0_.x, dx3, gx), qyz));   \
    accH.x += __builtin_amdgcn_exp2f(fmaf(dx4, fmaf(v0_.x, dx4, gx), qyz));   \
    accH.y += __builtin_amdgcn_exp2f(fmaf(dx5, fmaf(v0_.x, dx5, gx), qyz));   \
    accH.z += __builtin_amdgcn_exp2f(fmaf(dx6, fmaf(v0_.x, dx6, gx), qyz));   \
    accH.w += __builtin_amdgcn_exp2f(fmaf(dx7, fmaf(v0_.x, dx7, gx), qyz));   \
} while (0)

// Kernel 2: 512 blocks x 1024 threads (16 waves); block = one 8x8x8 tile
// (VPT=8 in x; lane -> (y,z)). No cull, no scan, no LDS list: read cnt,
// take the exact per-wave slice of the precompacted index list (sequential
// wave-uniform scalar loads), fetch records via s_load, run BODY8.
// Fixed-order 16-wave combine -> deterministic.
__global__ __launch_bounds__(1024, 8) void vox_kernel(
    const float* __restrict__ rec, const int* __restrict__ tilelist,
    const int* __restrict__ cntg, float* __restrict__ out, int N)
{
    __shared__ float4 plds[16][64];

    const int tid = threadIdx.x;
    const int lane = tid & 63, wave = tid >> 6;        // wave 0..15
    const int t = (blockIdx.x * 341) & 511;            // bijective scramble
    const int tX = t & 7, tY = (t >> 3) & 7, tZ = t >> 6;
    const int x0 = tX << 3;
    const int y = (tY << 3) + (lane & 7);
    const int z = (tZ << 3) + (lane >> 3);
    const float px = (x0 + 0.5f) * VOXF;
    const float py = (y + 0.5f) * VOXF;
    const float pz = (z + 0.5f) * VOXF;

    const int cnt = cntg[t];
    const int* tl = tilelist + (size_t)t * CAP;

    float4 accL, accH;
    accL.x = accL.y = accL.z = accL.w = 0.f;
    accH = accL;

    const int beg = (wave * cnt) >> 4;
    const int end = ((wave + 1) * cnt) >> 4;
    int p = beg;
    for (; p + 4 <= end; p += 4) {
        int i0 = tl[p], i1 = tl[p + 1], i2 = tl[p + 2], i3 = tl[p + 3];
        const float4* P0 = (const float4*)(rec + ((size_t)i0 << 4));
        const float4* P1 = (const float4*)(rec + ((size_t)i1 << 4));
        const float4* P2 = (const float4*)(rec + ((size_t)i2 << 4));
        const float4* P3 = (const float4*)(rec + ((size_t)i3 << 4));
        float4 a0 = P0[0], a1 = P0[1], a2 = P0[2];
        float4 b0 = P1[0], b1 = P1[1], b2 = P1[2];
        float4 c0 = P2[0], c1 = P2[1], c2 = P2[2];
        float4 d0 = P3[0], d1 = P3[1], d2 = P3[2];
        BODY8(a0, a1, a2);
        BODY8(b0, b1, b2);
        BODY8(c0, c1, c2);
        BODY8(d0, d1, d2);
    }
    for (; p < end; ++p) {
        int i0 = tl[p];
        const float4* P0 = (const float4*)(rec + ((size_t)i0 << 4));
        float4 a0 = P0[0], a1 = P0[1], a2 = P0[2];
        BODY8(a0, a1, a2);
    }

    // ---- combine: fixed wave order, two passes through plds ----
    const int v = (z << 12) + (y << 6) + x0;

    plds[wave][lane] = accL;
    __syncthreads();
    if (wave == 0) {
        float4 r = plds[0][lane];
        #pragma unroll
        for (int w = 1; w < 16; ++w) {
            float4 q = plds[w][lane];
            r.x += q.x; r.y += q.y; r.z += q.z; r.w += q.w;
        }
        *(float4*)&out[v] = r;
    }
    __syncthreads();
    plds[wave][lane] = accH;
    __syncthreads();
    if (wave == 0) {
        float4 r = plds[0][lane];
        #pragma unroll
        for (int w = 1; w < 16; ++w) {
            float4 q = plds[w][lane];
            r.x += q.x; r.y += q.y; r.z += q.z; r.w += q.w;
        }
        *(float4*)&out[v + 4] = r;
    }
}

extern "C" void kernel_launch(void* const* d_in, const int* in_sizes, int n_in,
                              void* d_out, int out_size, void* d_ws, size_t ws_size,
                              hipStream_t stream)
{
    const float* means  = (const float*)d_in[0];
    const float* dens   = (const float*)d_in[1];
    const float* scales = (const float*)d_in[2];
    const float* rots   = (const float*)d_in[3];
    float* out = (float*)d_out;
    float* ws  = (float*)d_ws;
    float* rec = ws + WS_REC;
    int* tilelist = (int*)(ws + WS_TL);
    int* cntg = (int*)(ws + WS_CNT);
    const int N = in_sizes[1];

    prep_kernel<<<516, 1024, 0, stream>>>(means, dens, scales, rots,
                                          rec, tilelist, cntg, out + NVOX, N);
    vox_kernel<<<512, 1024, 0, stream>>>(rec, tilelist, cntg, out, N);
}

// Round 24
// 24.683 us; speedup vs baseline: 1.2280x; 1.2280x over previous
//
#include <hip/hip_runtime.h>

#define GRIDN 64
#define NVOX (GRIDN * GRIDN * GRIDN)
#define VOXF (1.0f / 64.0f)
#define QCUT 10.0f               // contribution cut at e^-5 per (gaussian,voxel)
#define EXPSCL (-0.72134752044f) // -0.5 * log2(e)

// Workspace layout (float offsets), N=4096:
//  cullA[N] float4: (mux, muy, muz, rx)
//  cullB[N] float4: (ry, rz, sph_r2, 0)
//  rec[N]   4x float4 (64B stride, 3 used)
#define WS_CULLA 0
#define WS_CULLB (4 * 4096)
#define WS_REC   (8 * 4096)

__global__ __launch_bounds__(256) void prep_kernel(
    const float* __restrict__ means, const float* __restrict__ dens,
    const float* __restrict__ scales, const float* __restrict__ rots,
    float* __restrict__ ws, float* __restrict__ radii_out, int N)
{
    int i = blockIdx.x * 256 + threadIdx.x;
    if (i >= N) return;

    float qw = rots[i * 4 + 0], qx = rots[i * 4 + 1];
    float qy = rots[i * 4 + 2], qz = rots[i * 4 + 3];
    float inm = rsqrtf(qw * qw + qx * qx + qy * qy + qz * qz);
    qw *= inm; qx *= inm; qy *= inm; qz *= inm;
    float r00 = 1.f - 2.f * (qy * qy + qz * qz);
    float r01 = 2.f * (qx * qy - qw * qz);
    float r02 = 2.f * (qx * qz + qw * qy);
    float r10 = 2.f * (qx * qy + qw * qz);
    float r11 = 1.f - 2.f * (qx * qx + qz * qz);
    float r12 = 2.f * (qy * qz - qw * qx);
    float r20 = 2.f * (qx * qz - qw * qy);
    float r21 = 2.f * (qy * qz + qw * qx);
    float r22 = 1.f - 2.f * (qx * qx + qy * qy);

    float s0 = scales[i * 3 + 0], s1 = scales[i * 3 + 1], s2 = scales[i * 3 + 2];
    float v0 = s0 * s0, v1 = s1 * s1, v2 = s2 * s2;
    float i0 = 1.f / v0, i1 = 1.f / v1, i2 = 1.f / v2;

    // Sinv = R diag(1/s^2) R^T, scaled by EXPSCL (negative)
    float A = (r00 * r00 * i0 + r01 * r01 * i1 + r02 * r02 * i2) * EXPSCL;
    float B = (r10 * r10 * i0 + r11 * r11 * i1 + r12 * r12 * i2) * EXPSCL;
    float C = (r20 * r20 * i0 + r21 * r21 * i1 + r22 * r22 * i2) * EXPSCL;
    float D = (r00 * r10 * i0 + r01 * r11 * i1 + r02 * r12 * i2) * EXPSCL;
    float E = (r00 * r20 * i0 + r01 * r21 * i1 + r02 * r22 * i2) * EXPSCL;
    float F = (r10 * r20 * i0 + r11 * r21 * i1 + r12 * r22 * i2) * EXPSCL;

    // Covariance diagonal -> per-axis extents of {q <= qeff}
    float Cxx = r00 * r00 * v0 + r01 * r01 * v1 + r02 * r02 * v2;
    float Cyy = r10 * r10 * v0 + r11 * r11 * v1 + r12 * r12 * v2;
    float Czz = r20 * r20 * v0 + r21 * r21 * v1 + r22 * r22 * v2;

    float de = fmaxf(dens[i], 1e-30f);
    float qeff = fmaxf(QCUT + 2.0f * logf(de), 0.0f);   // de*exp(-q/2) < e^-5 cut
    float smax2 = fmaxf(v0, fmaxf(v1, v2));

    float mx = means[i * 3 + 0], my = means[i * 3 + 1], mz = means[i * 3 + 2];
    float4 ca; ca.x = mx; ca.y = my; ca.z = mz; ca.w = sqrtf(qeff * Cxx);
    float4 cb; cb.x = sqrtf(qeff * Cyy); cb.y = sqrtf(qeff * Czz);
    cb.z = qeff * smax2; cb.w = 0.f;
    ((float4*)(ws + WS_CULLA))[i] = ca;
    ((float4*)(ws + WS_CULLB))[i] = cb;

    float4* R = (float4*)(ws + WS_REC + (size_t)i * 16);
    float4 w0; w0.x = A; w0.y = B; w0.z = C; w0.w = 2.f * D;
    float4 w1; w1.x = 2.f * E; w1.y = 2.f * F; w1.z = -0.25f / A; w1.w = log2f(de);
    float4 w2; w2.x = mx; w2.y = my; w2.z = mz; w2.w = 0.f;
    R[0] = w0; R[1] = w1; R[2] = w2;

    float m = fmaxf(s0, fmaxf(s1, s2));
    radii_out[i] = ceilf(m * 3.0f * 64.0f);
}

// 8-voxel-strip body, NO strip test: contributions beyond the cut round to
// exp2(very negative) = 0 exactly, so skipping logic is unnecessary.
#define BODY8(v0_, v1_, v2_) do {                                             \
    float dy = py - v2_.y, dz = pz - v2_.z;                                   \
    float tt  = fmaf(v1_.y, dy, v0_.z * dz);                                  \
    float qyz = fmaf(v0_.y * dy, dy, fmaf(tt, dz, v1_.w));                    \
    float gx  = fmaf(v0_.w, dy, v1_.x * dz);                                  \
    float dx0 = px - v2_.x;                                                   \
    float dx1 = dx0 + VOXF,        dx2 = dx0 + 2.f * VOXF;                    \
    float dx3 = dx0 + 3.f * VOXF,  dx4 = dx0 + 4.f * VOXF;                    \
    float dx5 = dx0 + 5.f * VOXF,  dx6 = dx0 + 6.f * VOXF;                    \
    float dx7 = dx0 + 7.f * VOXF;                                             \
    accL.x += __builtin_amdgcn_exp2f(fmaf(dx0, fmaf(v0_.x, dx0, gx), qyz));   \
    accL.y += __builtin_amdgcn_exp2f(fmaf(dx1, fmaf(v0_.x, dx1, gx), qyz));   \
    accL.z += __builtin_amdgcn_exp2f(fmaf(dx2, fmaf(v0_.x, dx2, gx), qyz));   \
    accL.w += __builtin_amdgcn_exp2f(fmaf(dx3, fmaf(v0_.x, dx3, gx), qyz));   \
    accH.x += __builtin_amdgcn_exp2f(fmaf(dx4, fmaf(v0_.x, dx4, gx), qyz));   \
    accH.y += __builtin_amdgcn_exp2f(fmaf(dx5, fmaf(v0_.x, dx5, gx), qyz));   \
    accH.z += __builtin_amdgcn_exp2f(fmaf(dx6, fmaf(v0_.x, dx6, gx), qyz));   \
    accH.w += __builtin_amdgcn_exp2f(fmaf(dx7, fmaf(v0_.x, dx7, gx), qyz));   \
} while (0)

// 512 blocks x 1024 threads (16 waves); block = one 8x8x8 tile (VPT=8 in x;
// lane -> (y,z)). Pass A: table cull, 4 chunks/wave -> ballot masks.
// Shuffle-scan -> stable scatter -> EXACT per-wave slices (no padding):
// beg=(w*cnt)>>4, end=((w+1)*cnt)>>4; unroll-4 bulk + 0..3 remainder.
// Records via wave-uniform s_load. Fixed-order 16-wave combine.
__global__ __launch_bounds__(1024, 8) void vox_kernel(
    const float* __restrict__ ws, float* __restrict__ out, int N)
{
    __shared__ unsigned long long cmask[64];
    __shared__ int slist[3072];
    __shared__ float4 plds[16][64];

    const float* rec = ws + WS_REC;
    const int tid = threadIdx.x;
    const int lane = tid & 63, wave = tid >> 6;        // wave 0..15
    const int t = (blockIdx.x * 341) & 511;            // bijective scramble
    const int tX = t & 7, tY = (t >> 3) & 7, tZ = t >> 6;   // 8x8x8 tiles
    const int x0 = tX << 3;
    const int y = (tY << 3) + (lane & 7);
    const int z = (tZ << 3) + (lane >> 3);
    const float px = (x0 + 0.5f) * VOXF;
    const float py = (y + 0.5f) * VOXF;
    const float pz = (z + 0.5f) * VOXF;

    const float lox = (x0 + 0.5f) * VOXF,          hix = (x0 + 7.5f) * VOXF;
    const float loy = ((tY << 3) + 0.5f) * VOXF,   hiy = ((tY << 3) + 7.5f) * VOXF;
    const float loz = ((tZ << 3) + 0.5f) * VOXF,   hiz = ((tZ << 3) + 7.5f) * VOXF;

    // ---- pass A: cull 4 chunks/wave from the cull tables ----
    const int nch = (N + 63) >> 6;
    #pragma unroll
    for (int k = 0; k < 4; ++k) {
        const int c = (k << 4) | wave;
        unsigned long long bal = 0ull;
        if (c < nch) {
            const int gi = (c << 6) + lane;
            const int gc = gi < N ? gi : N - 1;
            float4 ca = ((const float4*)(ws + WS_CULLA))[gc];
            float4 cb = ((const float4*)(ws + WS_CULLB))[gc];
            float cx = fminf(fmaxf(ca.x, lox), hix) - ca.x;
            float cy = fminf(fmaxf(ca.y, loy), hiy) - ca.y;
            float cz = fminf(fmaxf(ca.z, loz), hiz) - ca.z;
            float d2 = fmaf(cx, cx, fmaf(cy, cy, cz * cz));
            bool keep = (gi < N) && (d2 <= cb.z)
                && (ca.x + ca.w >= lox) && (ca.x - ca.w <= hix)
                && (ca.y + cb.x >= loy) && (ca.y - cb.x <= hiy)
                && (ca.z + cb.y >= loz) && (ca.z - cb.y <= hiz);
            bal = __ballot(keep);
        }
        if (lane == 0) cmask[c] = bal;
    }
    __syncthreads();

    // ---- scan over 64 chunk-masks (all waves compute identically) ----
    unsigned long long mk = cmask[lane];
    int pc = __popcll(mk);
    int incl = pc;
    #pragma unroll
    for (int d = 1; d < 64; d <<= 1) {
        int t2 = __shfl_up(incl, d, 64);
        if (lane >= d) incl += t2;
    }
    const int excl = incl - pc;
    int cnt = __builtin_amdgcn_readlane(incl, 63);
    if (cnt > 3072) cnt = 3072;   // far beyond worst case; safety clamp

    // ---- pass B: stable scatter of survivor indices ----
    #pragma unroll
    for (int k = 0; k < 4; ++k) {
        const int c = (k << 4) | wave;
        unsigned long long mc = cmask[c];
        if (mc == 0ull) continue;
        int bse = __builtin_amdgcn_readlane(excl, c);
        if ((mc >> lane) & 1ull) {
            int pre = __popcll(mc & ((1ull << lane) - 1ull));
            int pos = bse + pre;
            if (pos < 3072) slist[pos] = (c << 6) + lane;
        }
    }
    __syncthreads();

    float4 accL, accH;
    accL.x = accL.y = accL.z = accL.w = 0.f;
    accH = accL;

    // ---- phase 2: exact per-wave slice, readlane indices + s_load records ----
    const int beg = (wave * cnt) >> 4;
    const int end = ((wave + 1) * cnt) >> 4;
    for (int base = beg; base < end; base += 64) {
        int src = base + lane;
        int vidx = slist[src < cnt ? src : cnt - 1];   // 1 ds_read / <=64 slots
        int m = end - base; if (m > 64) m = 64;
        int j = 0;
        for (; j + 4 <= m; j += 4) {
            int i0 = __builtin_amdgcn_readlane(vidx, j);
            int i1 = __builtin_amdgcn_readlane(vidx, j + 1);
            int i2 = __builtin_amdgcn_readlane(vidx, j + 2);
            int i3 = __builtin_amdgcn_readlane(vidx, j + 3);
            const float4* P0 = (const float4*)(rec + ((size_t)i0 << 4));
            const float4* P1 = (const float4*)(rec + ((size_t)i1 << 4));
            const float4* P2 = (const float4*)(rec + ((size_t)i2 << 4));
            const float4* P3 = (const float4*)(rec + ((size_t)i3 << 4));
            float4 a0 = P0[0], a1 = P0[1], a2 = P0[2];
            float4 b0 = P1[0], b1 = P1[1], b2 = P1[2];
            float4 c0 = P2[0], c1 = P2[1], c2 = P2[2];
            float4 d0 = P3[0], d1 = P3[1], d2 = P3[2];
            BODY8(a0, a1, a2);
            BODY8(b0, b1, b2);
            BODY8(c0, c1, c2);
            BODY8(d0, d1, d2);
        }
        for (; j < m; ++j) {
            int i0 = __builtin_amdgcn_readlane(vidx, j);
            const float4* P0 = (const float4*)(rec + ((size_t)i0 << 4));
            float4 a0 = P0[0], a1 = P0[1], a2 = P0[2];
            BODY8(a0, a1, a2);
        }
    }

    // ---- combine: fixed wave order, two passes through plds ----
    const int v = (z << 12) + (y << 6) + x0;

    plds[wave][lane] = accL;
    __syncthreads();
    if (wave == 0) {
        float4 r = plds[0][lane];
        #pragma unroll
        for (int w = 1; w < 16; ++w) {
            float4 p = plds[w][lane];
            r.x += p.x; r.y += p.y; r.z += p.z; r.w += p.w;
        }
        *(float4*)&out[v] = r;
    }
    __syncthreads();
    plds[wave][lane] = accH;
    __syncthreads();
    if (wave == 0) {
        float4 r = plds[0][lane];
        #pragma unroll
        for (int w = 1; w < 16; ++w) {
            float4 p = plds[w][lane];
            r.x += p.x; r.y += p.y; r.z += p.z; r.w += p.w;
        }
        *(float4*)&out[v + 4] = r;
    }
}

extern "C" void kernel_launch(void* const* d_in, const int* in_sizes, int n_in,
                              void* d_out, int out_size, void* d_ws, size_t ws_size,
                              hipStream_t stream)
{
    const float* means  = (const float*)d_in[0];
    const float* dens   = (const float*)d_in[1];
    const float* scales = (const float*)d_in[2];
    const float* rots   = (const float*)d_in[3];
    float* out = (float*)d_out;
    float* ws  = (float*)d_ws;
    const int N = in_sizes[1];

    prep_kernel<<<(N + 255) / 256, 256, 0, stream>>>(means, dens, scales, rots,
                                                     ws, out + NVOX, N);
    vox_kernel<<<512, 1024, 0, stream>>>(ws, out, N);
}